// Round 5
// baseline (512.976 us; speedup 1.0000x reference)
//
#include <hip/hip_runtime.h>

// ---------------------------------------------------------------------------
// DecoderLayer forward: B=4, S=2048, D=1024, F=4096, single-head causal attn.
// Round 18 = round 17 resubmitted verbatim (r17 bench failed on GPU
// acquisition timeout; no data). Rationale recap:
// Evidence through r16: staging runs ~17.8 B/cyc/CU ONLY with >=2
// co-resident (unsynchronized) blocks per CU; every 1-block/CU variant (sbuf,
// dbuf+sync, dbuf+counted-vmcnt) caps at 10.6-11.8 B/cyc. So:
//   - FC2 reverts to the 128x128 dbuf/__syncthreads kernel (97.9us measured
//     at 2 blocks/CU); the 256x128 family (107-120us) is abandoned.
//   - NEW: n-per-XCD supertile remap (NSWAP) on FC2/Wo/PV/FC1. XCD id ==
//     dispatch linear%8 == within&7; making that the N index pins each XCD's
//     B-slice (0.25-1 MB) in its private 4MB L2 for the whole kernel ->
//     B-restage becomes L2-hit, L3 traffic drops (FC2: 576->520 MB). Probes
//     whether the ~10.4 TB/s aggregate staging cap has a fabric component.
//   - QKV/FC1 keep the 256x256 counted-vmcnt kernel (r16 best for them).
// ---------------------------------------------------------------------------

typedef __attribute__((ext_vector_type(8))) short short8;   // 8 x bf16 (4 VGPR)
typedef __attribute__((ext_vector_type(4))) float f32x4;    // MFMA C/D

#define DMODEL 1024
#define DFF    4096
#define NB     4
#define SEQ    2048
#define NROWS  (NB * SEQ)   // 8192
#define QKVN   (3 * DMODEL) // 3072

__device__ __forceinline__ unsigned short f2bf(float f) {
  union { float f; unsigned u; } v; v.f = f;
  unsigned r = v.u + 0x7FFFu + ((v.u >> 16) & 1u);  // round-to-nearest-even
  return (unsigned short)(r >> 16);
}
__device__ __forceinline__ float bf2f(unsigned short h) {
  union { unsigned u; float f; } v; v.u = ((unsigned)h) << 16;
  return v.f;
}

// async global -> LDS, 16 bytes per lane; lds base must be wave-uniform,
// lane i's data lands at lds + i*16 (m104/m108 constraint).
__device__ __forceinline__ void g2l16(const unsigned short* g, unsigned short* lds) {
  __builtin_amdgcn_global_load_lds(
      (const __attribute__((address_space(1))) void*)g,
      (__attribute__((address_space(3))) void*)lds,
      16, 0, 0);
}

// barrier-entry fence: all waves' current-tile staging visible, and no LDS
// read may be scheduled between the per-wave wait and the barrier.
#define BAR_ACQ() do {                         \
    __builtin_amdgcn_s_barrier();              \
    asm volatile("" ::: "memory");             \
    __builtin_amdgcn_sched_barrier(0);         \
  } while (0)
// barrier-exit fence: compute's LDS reads may not sink past the barrier into
// the stage region that overwrites the buffer.
#define BAR_REL() do {                         \
    __builtin_amdgcn_sched_barrier(0);         \
    asm volatile("" ::: "memory");             \
    __builtin_amdgcn_s_barrier();              \
  } while (0)

// ---- fp32 -> bf16 convert, all 6 weight tensors in one launch ----
__global__ __launch_bounds__(256) void cvt_bf16_all(
    const float* __restrict__ s0, const float* __restrict__ s1,
    const float* __restrict__ s2, const float* __restrict__ s3,
    const float* __restrict__ s4, const float* __restrict__ s5,
    unsigned short* __restrict__ d0, unsigned short* __restrict__ d1,
    unsigned short* __restrict__ d2, unsigned short* __restrict__ d3,
    unsigned short* __restrict__ d4, unsigned short* __restrict__ d5,
    int n_small, int n_big) {
  const int z = blockIdx.y;
  const float* src; unsigned short* dst; int n4;
  switch (z) {
    case 0: src = s0; dst = d0; n4 = n_small; break;
    case 1: src = s1; dst = d1; n4 = n_small; break;
    case 2: src = s2; dst = d2; n4 = n_small; break;
    case 3: src = s3; dst = d3; n4 = n_small; break;
    case 4: src = s4; dst = d4; n4 = n_big;   break;
    default: src = s5; dst = d5; n4 = n_big;  break;
  }
  int i = blockIdx.x * 256 + threadIdx.x;
  if (i >= n4) return;
  float4 v = reinterpret_cast<const float4*>(src)[i];
  ushort4 o;
  o.x = f2bf(v.x); o.y = f2bf(v.y); o.z = f2bf(v.z); o.w = f2bf(v.w);
  reinterpret_cast<ushort4*>(dst)[i] = o;
}

// ---- LayerNorm over D=1024, one 256-thread block per row, bf16 out ----
__global__ __launch_bounds__(256) void ln_bf16(const float* __restrict__ x,
                                               const float* __restrict__ g,
                                               const float* __restrict__ b,
                                               unsigned short* __restrict__ out) {
  int row = blockIdx.x;
  int t = threadIdx.x;
  const float* xr = x + (size_t)row * DMODEL;
  float4 v = reinterpret_cast<const float4*>(xr)[t];
  float s  = v.x + v.y + v.z + v.w;
  float s2 = v.x*v.x + v.y*v.y + v.z*v.z + v.w*v.w;
  #pragma unroll
  for (int off = 32; off > 0; off >>= 1) {
    s  += __shfl_down(s, off);
    s2 += __shfl_down(s2, off);
  }
  __shared__ float rs[4], rs2[4], stats[2];
  int lane = t & 63, wave = t >> 6;
  if (lane == 0) { rs[wave] = s; rs2[wave] = s2; }
  __syncthreads();
  if (t == 0) {
    float ts  = rs[0] + rs[1] + rs[2] + rs[3];
    float ts2 = rs2[0] + rs2[1] + rs2[2] + rs2[3];
    float mu = ts / DMODEL;
    stats[0] = mu;
    stats[1] = rsqrtf(ts2 / DMODEL - mu * mu + 1e-5f);
  }
  __syncthreads();
  float mu = stats[0], rstd = stats[1];
  float4 gg = reinterpret_cast<const float4*>(g)[t];
  float4 bb = reinterpret_cast<const float4*>(b)[t];
  ushort4 o;
  o.x = f2bf((v.x - mu) * rstd * gg.x + bb.x);
  o.y = f2bf((v.y - mu) * rstd * gg.y + bb.y);
  o.z = f2bf((v.z - mu) * rstd * gg.z + bb.z);
  o.w = f2bf((v.w - mu) * rstd * gg.w + bb.w);
  reinterpret_cast<ushort4*>(out + (size_t)row * DMODEL)[t] = o;
}

// ---- bf16 tile transpose: in [R][C] (row stride ldin) -> out [C][R] ----
__global__ __launch_bounds__(256) void transpose_bf16(const unsigned short* __restrict__ in,
                                                      unsigned short* __restrict__ out,
                                                      int R, int C, int ldin,
                                                      size_t sIn, size_t sOut) {
  __shared__ unsigned short tile[32][33];
  in  += (size_t)blockIdx.z * sIn;
  out += (size_t)blockIdx.z * sOut;
  int c0 = blockIdx.x * 32, r0 = blockIdx.y * 32;
  int tx = threadIdx.x & 31, ty = threadIdx.x >> 5;  // 32 x 8
  #pragma unroll
  for (int i = 0; i < 4; ++i)
    tile[ty + i * 8][tx] = in[(size_t)(r0 + ty + i * 8) * ldin + c0 + tx];
  __syncthreads();
  #pragma unroll
  for (int i = 0; i < 4; ++i)
    out[(size_t)(c0 + ty + i * 8) * R + r0 + tx] = tile[tx][ty + i * 8];
}

// ---- causal row softmax: bf16 scores -> bf16 probs; writes only the
// k-range PV will read (k < ceil((q+1)/128)*128) ----
__global__ __launch_bounds__(256) void softmax_causal(const unsigned short* __restrict__ Sc,
                                                      unsigned short* __restrict__ P) {
  const int q = blockIdx.x, b = blockIdx.y;
  const unsigned short* srow = Sc + ((size_t)b * SEQ + q) * SEQ;
  unsigned short* prow = P + ((size_t)b * SEQ + q) * SEQ;
  const int L = q + 1;
  const int kcap = (q & ~127) + 128;   // PV reads k < m0+128 = kcap for row q
  const int t = threadIdx.x;
  __shared__ float red[4];
  __shared__ float bc;

  float mx = -1e30f;
  for (int i = t; i < L; i += 256) mx = fmaxf(mx, bf2f(srow[i]));
  #pragma unroll
  for (int off = 32; off > 0; off >>= 1) mx = fmaxf(mx, __shfl_down(mx, off));
  if ((t & 63) == 0) red[t >> 6] = mx;
  __syncthreads();
  if (t == 0) bc = fmaxf(fmaxf(red[0], red[1]), fmaxf(red[2], red[3]));
  __syncthreads();
  mx = bc;

  float sum = 0.f;
  for (int i = t; i < L; i += 256) sum += __expf(bf2f(srow[i]) - mx);
  #pragma unroll
  for (int off = 32; off > 0; off >>= 1) sum += __shfl_down(sum, off);
  __syncthreads();            // red reuse guard
  if ((t & 63) == 0) red[t >> 6] = sum;
  __syncthreads();
  if (t == 0) bc = 1.0f / (red[0] + red[1] + red[2] + red[3]);
  __syncthreads();
  float inv = bc;

  for (int i = t; i < kcap; i += 256) {
    float p = (i < L) ? __expf(bf2f(srow[i]) - mx) * inv : 0.f;
    prow[i] = f2bf(p);
  }
}

// ---------------------------------------------------------------------------
// 128x128 GEMM (scores / PV / Wo / FC2): 4 waves (2x2 of 64x64), BK=64,
// dbuf LDS, 1 barrier/iter, global_load_lds width=16, XOR swizzle (0 bank
// conflicts), 8x8 super-tile remap; 2 blocks/CU cover the __syncthreads
// vmcnt drain (17.8 B/cyc measured).
// NSWAP: within&7 (== dispatch linear%8 == XCD id) selects the N block, so
// each XCD's B-slice stays resident in its private L2 for the whole kernel.
// Requires gridDim.y % 8 == 0.
// ---------------------------------------------------------------------------
template<bool OUT_F32, bool ADD_BIAS, bool RELU, bool ADD_RESID,
         bool CAUSAL_SKIP, bool CAUSAL_KLIM, bool SCALE, bool NSWAP>
__global__ __launch_bounds__(256) void gemm_bt(
    const unsigned short* __restrict__ A, size_t sA,
    const unsigned short* __restrict__ B, size_t sB,
    void* __restrict__ Cv, size_t sC,
    const float* __restrict__ bias,
    const float* __restrict__ resid, size_t sR,
    int K, int lda, int ldb, int ldc, float scale) {
  const int linear = blockIdx.y * gridDim.x + blockIdx.x;
  const int tileId = linear >> 6;
  const int within = linear & 63;
  int m_blk, n_blk;
  if (NSWAP) {                                 // XCD id == within&7 -> N
    const int nGroups = gridDim.y >> 3;
    n_blk = (tileId % nGroups) * 8 + (within & 7);
    m_blk = (tileId / nGroups) * 8 + (within >> 3);
  } else {
    const int mGroups = gridDim.x >> 3;
    m_blk = (tileId % mGroups) * 8 + (within & 7);
    n_blk = (tileId / mGroups) * 8 + (within >> 3);
  }
  const int m0 = m_blk * 128;
  const int n0 = n_blk * 128;
  if (CAUSAL_SKIP && n0 > m0 + 127) return;  // block fully masked
  const int bz = blockIdx.z;
  A += (size_t)bz * sA;
  B += (size_t)bz * sB;

  __shared__ unsigned short As[2][128 * 64];   // 2 x 16 KB, XOR-swizzled
  __shared__ unsigned short Bs[2][128 * 64];

  const int t = threadIdx.x;
  const int lane = t & 63;
  const int wave = t >> 6;
  const int wm = (wave >> 1) * 64;
  const int wn = (wave & 1) * 64;
  const int lr = lane & 15;
  const int lq = lane >> 4;

  const int srow = lane >> 3;                  // 0..7
  const int pcol = ((lane & 7) ^ srow) * 8;    // XOR-swizzled fetch col

  f32x4 acc[4][4] = {};

  const int kEnd  = CAUSAL_KLIM ? min(K, m0 + 128) : K;
  const int nIter = kEnd >> 6;                 // BK = 64

  auto stage = [&](int buf, int kt) {
    #pragma unroll
    for (int i = 0; i < 4; ++i) {
      const int c = wave * 4 + i;              // chunk 0..15
      const int row = c * 8 + srow;
      g2l16(&A[(size_t)(m0 + row) * lda + kt + pcol], &As[buf][c * 512]);
      g2l16(&B[(size_t)(n0 + row) * ldb + kt + pcol], &Bs[buf][c * 512]);
    }
  };

  stage(0, 0);

  for (int it = 0; it < nIter; ++it) {
    __syncthreads();   // drains vmcnt: buf[it&1] ready; other free to fill
    if (it + 1 < nIter) stage((it + 1) & 1, (it + 1) << 6);
    const unsigned short* Ab = As[it & 1];
    const unsigned short* Bb = Bs[it & 1];
    #pragma unroll
    for (int kk = 0; kk < 2; ++kk) {
      short8 af[4], bfr[4];
      #pragma unroll
      for (int i = 0; i < 4; ++i) {
        const int r = wm + i * 16 + lr;
        af[i] = *reinterpret_cast<const short8*>(
            &Ab[r * 64 + (((kk * 4 + lq) ^ (r & 7)) * 8)]);
      }
      #pragma unroll
      for (int j = 0; j < 4; ++j) {
        const int r = wn + j * 16 + lr;
        bfr[j] = *reinterpret_cast<const short8*>(
            &Bb[r * 64 + (((kk * 4 + lq) ^ (r & 7)) * 8)]);
      }
      #pragma unroll
      for (int i = 0; i < 4; ++i)
        #pragma unroll
        for (int j = 0; j < 4; ++j)
          acc[i][j] = __builtin_amdgcn_mfma_f32_16x16x32_bf16(af[i], bfr[j], acc[i][j], 0, 0, 0);
    }
  }

  float* Cf = (float*)Cv + (size_t)bz * sC;
  unsigned short* Ch = (unsigned short*)Cv + (size_t)bz * sC;
  const float* rr = ADD_RESID ? (resid + (size_t)bz * sR) : nullptr;
  #pragma unroll
  for (int i = 0; i < 4; ++i) {
    #pragma unroll
    for (int j = 0; j < 4; ++j) {
      #pragma unroll
      for (int r = 0; r < 4; ++r) {
        // C/D layout (verified m89/m91): col = lane&15, row = (lane>>4)*4 + reg
        int row = m0 + wm + i * 16 + lq * 4 + r;
        int col = n0 + wn + j * 16 + lr;
        float v = acc[i][j][r];
        if (SCALE)     v *= scale;
        if (ADD_BIAS)  v += bias[col];
        if (RELU)      v = fmaxf(v, 0.0f);
        if (ADD_RESID) v += rr[(size_t)row * ldc + col];
        if (OUT_F32) Cf[(size_t)row * ldc + col] = v;
        else         Ch[(size_t)row * ldc + col] = f2bf(v);
      }
    }
  }
}

// ---------------------------------------------------------------------------
// 256x256 GEMM (FC1 / QKV): 1024 threads = 16 waves (4x4 of 64x64), BK=64,
// dbuf 128 KB LDS, counted-vmcnt pipeline (per-wave 4 loads/stage, wait
// vmcnt(4) leaves the next stage in flight across both raw barriers).
// NSWAP (FC1, GY=16): XCD id == within&7 -> N block; per-XCD B-slice
// (2 x 0.5 MB) L2-resident. QKV (GY=12) uses identity map.
// ---------------------------------------------------------------------------
template<bool OUT_F32, bool ADD_BIAS, bool RELU, bool NSWAP>
__global__ __launch_bounds__(1024) void gemm_bt256(
    const unsigned short* __restrict__ A,
    const unsigned short* __restrict__ B,
    void* __restrict__ Cv,
    const float* __restrict__ bias,
    int K, int lda, int ldb, int ldc) {
  int m_blk, n_blk;
  if (NSWAP && (gridDim.y & 7) == 0) {         // XCD id -> N
    const int linear = blockIdx.y * gridDim.x + blockIdx.x;
    const int tileId = linear >> 6;
    const int within = linear & 63;
    const int nGroups = gridDim.y >> 3;
    n_blk = (tileId % nGroups) * 8 + (within & 7);
    m_blk = (tileId / nGroups) * 8 + (within >> 3);
  } else if ((gridDim.y & 7) == 0) {           // 8x8 super-tile remap
    const int GX = gridDim.x;
    const int linear = blockIdx.y * GX + blockIdx.x;
    const int tileId = linear >> 6;
    const int within = linear & 63;
    const int mGroups = GX >> 3;
    m_blk = (tileId % mGroups) * 8 + (within & 7);
    n_blk = (tileId / mGroups) * 8 + (within >> 3);
  } else {                                     // identity (e.g. QKV GY=12)
    m_blk = blockIdx.x;
    n_blk = blockIdx.y;
  }
  const int m0 = m_blk * 256;
  const int n0 = n_blk * 256;

  __shared__ unsigned short As[2][256 * 64];   // 2 x 32 KB, XOR-swizzled
  __shared__ unsigned short Bs[2][256 * 64];   // 2 x 32 KB  (128 KB total)

  const int t = threadIdx.x;
  const int lane = t & 63;
  const int wave = t >> 6;                     // 0..15
  const int wm = (wave >> 2) * 64;             // 0,64,128,192
  const int wn = (wave & 3) * 64;              // 0,64,128,192
  const int lr = lane & 15;
  const int lq = lane >> 4;

  const int srow = lane >> 3;                  // 0..7
  const int pcol = ((lane & 7) ^ srow) * 8;    // XOR-swizzled fetch col

  f32x4 acc[4][4] = {};
  const int nIter = K >> 6;                    // BK = 64 (nIter >= 2 here)

  auto stage = [&](int buf, int kt) {
    #pragma unroll
    for (int i = 0; i < 2; ++i) {
      const int c = wave * 2 + i;              // chunk 0..31
      const int row = c * 8 + srow;
      g2l16(&A[(size_t)(m0 + row) * lda + kt + pcol], &As[buf][c * 512]);
      g2l16(&B[(size_t)(n0 + row) * ldb + kt + pcol], &Bs[buf][c * 512]);
    }
  };

  stage(0, 0);        // 4 loads/wave
  stage(1, 64);       // 4 more -> 8 outstanding/wave

  for (int it = 0; it < nIter; ++it) {
    // own stage(it) complete; stage(it+1)'s 4 loads may remain in flight
    if (it + 1 < nIter) asm volatile("s_waitcnt vmcnt(4)" ::: "memory");
    else                asm volatile("s_waitcnt vmcnt(0)" ::: "memory");
    BAR_ACQ();         // all waves' stage(it) complete
    const unsigned short* Ab = As[it & 1];
    const unsigned short* Bb = Bs[it & 1];
    #pragma unroll
    for (int kk = 0; kk < 2; ++kk) {
      short8 af[4], bfr[4];
      #pragma unroll
      for (int i = 0; i < 4; ++i) {
        const int r = wm + i * 16 + lr;
        af[i] = *reinterpret_cast<const short8*>(
            &Ab[r * 64 + (((kk * 4 + lq) ^ (r & 7)) * 8)]);
      }
      #pragma unroll
      for (int j = 0; j < 4; ++j) {
        const int r = wn + j * 16 + lr;
        bfr[j] = *reinterpret_cast<const short8*>(
            &Bb[r * 64 + (((kk * 4 + lq) ^ (r & 7)) * 8)]);
      }
      #pragma unroll
      for (int i = 0; i < 4; ++i)
        #pragma unroll
        for (int j = 0; j < 4; ++j)
          acc[i][j] = __builtin_amdgcn_mfma_f32_16x16x32_bf16(af[i], bfr[j], acc[i][j], 0, 0, 0);
    }
    BAR_REL();         // all waves done reading buf[it&1]
    if (it + 2 < nIter) stage(it & 1, (it + 2) << 6);
  }

  float* Cf = (float*)Cv;
  unsigned short* Ch = (unsigned short*)Cv;
  #pragma unroll
  for (int i = 0; i < 4; ++i) {
    #pragma unroll
    for (int j = 0; j < 4; ++j) {
      #pragma unroll
      for (int r = 0; r < 4; ++r) {
        int row = m0 + wm + i * 16 + lq * 4 + r;
        int col = n0 + wn + j * 16 + lr;
        float v = acc[i][j][r];
        if (ADD_BIAS) v += bias[col];
        if (RELU)     v = fmaxf(v, 0.0f);
        if (OUT_F32) Cf[(size_t)row * ldc + col] = v;
        else         Ch[(size_t)row * ldc + col] = f2bf(v);
      }
    }
  }
}

// ---------------------------------------------------------------------------
extern "C" void kernel_launch(void* const* d_in, const int* in_sizes, int n_in,
                              void* d_out, int out_size, void* d_ws, size_t ws_size,
                              hipStream_t stream) {
  const float* x    = (const float*)d_in[0];
  const float* Wq   = (const float*)d_in[1];
  const float* Wk   = (const float*)d_in[2];
  const float* Wv   = (const float*)d_in[3];
  const float* Wo   = (const float*)d_in[4];
  const float* fc1w = (const float*)d_in[5];
  const float* fc1b = (const float*)d_in[6];
  const float* fc2w = (const float*)d_in[7];
  const float* fc2b = (const float*)d_in[8];
  const float* ln1g = (const float*)d_in[9];
  const float* ln1b = (const float*)d_in[10];
  const float* ln2g = (const float*)d_in[11];
  const float* ln2b = (const float*)d_in[12];
  float* out = (float*)d_out;

  // workspace carve-up with liveness aliasing
  char* w = (char*)d_ws;
  auto alloc = [&](size_t bytes) {
    char* p = w;
    w += (bytes + 255) & ~(size_t)255;
    return p;
  };
  typedef unsigned short u16;
  u16* wqkv_b = (u16*)alloc((size_t)QKVN * DMODEL * 2);   // stacked Q|K|V
  u16* wq_b   = wqkv_b;
  u16* wk_b   = wqkv_b + (size_t)DMODEL * DMODEL;
  u16* wv_b   = wqkv_b + (size_t)2 * DMODEL * DMODEL;
  u16* wo_b   = (u16*)alloc((size_t)DMODEL * DMODEL * 2);
  u16* fc1w_b = (u16*)alloc((size_t)DFF * DMODEL * 2);
  u16* fc2w_b = (u16*)alloc((size_t)DMODEL * DFF * 2);
  u16* xn     = (u16*)alloc((size_t)NROWS * DMODEL * 2);
  u16* qkv    = (u16*)alloc((size_t)NROWS * QKVN * 2);    // 48 MB
  u16* vt     = (u16*)alloc((size_t)NROWS * DMODEL * 2);
  u16* ctx    = (u16*)alloc((size_t)NROWS * DMODEL * 2);
  u16* xn2    = (u16*)alloc((size_t)NROWS * DMODEL * 2);
  // Region A (64 MB): sc_h (bf16 scores, steps 5-6) aliased with hbuf (10-11)
  char* regA  = (char*)alloc((size_t)NB * SEQ * SEQ * 4);
  u16*   sc_h = (u16*)regA;
  u16*   hbuf = (u16*)regA;
  // Region B (32 MB): Pbuf (steps 6-7) aliased with x1 (steps 8-11)
  char* regB  = (char*)alloc((size_t)NB * SEQ * SEQ * 2);
  u16*   Pbuf = (u16*)regB;
  float* x1   = (float*)regB;

  // 1. weights -> bf16 (single launch; z selects tensor)
  {
    int n_small = DMODEL * DMODEL / 4;
    int n_big   = DFF * DMODEL / 4;
    dim3 g((n_big + 255) / 256, 6);
    cvt_bf16_all<<<g, 256, 0, stream>>>(Wq, Wk, Wv, Wo, fc1w, fc2w,
                                        wq_b, wk_b, wv_b, wo_b, fc1w_b, fc2w_b,
                                        n_small, n_big);
  }

  // 2. LN1
  ln_bf16<<<dim3(NROWS), 256, 0, stream>>>(x, ln1g, ln1b, xn);

  // 3. merged QKV projection: [8192,1024] x [3072,1024]^T -> qkv [8192,3072]
  //    256x256 dbuf counted-vmcnt, grid 32x12 = 384 blocks (identity map)
  gemm_bt256<false,false,false,false><<<dim3(NROWS / 256, QKVN / 256), 1024, 0, stream>>>(
      xn, wqkv_b, qkv, nullptr, DMODEL, DMODEL, DMODEL, QKVN);
  const u16* qb = qkv;                 // lda = QKVN
  const u16* kb = qkv + DMODEL;
  const u16* vb = qkv + 2 * DMODEL;

  // 4. V^T per batch: [2048,1024] (stride 3072) -> [1024,2048]
  transpose_bf16<<<dim3(DMODEL / 32, SEQ / 32, NB), 256, 0, stream>>>(
      vb, vt, SEQ, DMODEL, QKVN, (size_t)SEQ * QKVN, (size_t)DMODEL * SEQ);

  // 5. scores = Q K^T / sqrt(D), bf16 out, skip fully-masked blocks
  {
    dim3 g(SEQ / 128, SEQ / 128, NB);
    gemm_bt<false,false,false,false,true,false,true,false><<<g, 256, 0, stream>>>(
        qb, (size_t)SEQ * QKVN, kb, (size_t)SEQ * QKVN, sc_h, (size_t)SEQ * SEQ,
        nullptr, nullptr, 0, DMODEL, QKVN, QKVN, SEQ, 0.03125f /*1/sqrt(1024)*/);
  }

  // 6. causal softmax (bf16 in/out; writes only k < ceil((q+1)/128)*128)
  softmax_causal<<<dim3(SEQ, NB), 256, 0, stream>>>(sc_h, Pbuf);

  // 7. ctx = P V  (K-reduction bounded by causality), NSWAP: vt slice/XCD
  {
    dim3 g(SEQ / 128, DMODEL / 128, NB);
    gemm_bt<false,false,false,false,false,true,false,true><<<g, 256, 0, stream>>>(
        Pbuf, (size_t)SEQ * SEQ, vt, (size_t)DMODEL * SEQ, ctx, (size_t)SEQ * DMODEL,
        nullptr, nullptr, 0, SEQ, SEQ, SEQ, DMODEL, 1.f);
  }

  // 8. x1 = x + ctx Wo^T  (fp32)  -- x1 aliases Pbuf (dead after step 7)
  {
    dim3 g(NROWS / 128, DMODEL / 128, 1);
    gemm_bt<true,false,false,true,false,false,false,true><<<g, 256, 0, stream>>>(
        ctx, 0, wo_b, 0, x1, 0, nullptr, x, 0, DMODEL, DMODEL, DMODEL, DMODEL, 1.f);
  }

  // 9. LN2
  ln_bf16<<<dim3(NROWS), 256, 0, stream>>>(x1, ln2g, ln2b, xn2);

  // 10. h = relu(xn2 fc1_w^T + fc1_b)  bf16 [8192,4096]
  //     256x256 dbuf counted-vmcnt + NSWAP, grid 32x16 = 512 blocks
  gemm_bt256<false,true,true,true><<<dim3(NROWS / 256, DFF / 256), 1024, 0, stream>>>(
      xn2, fc1w_b, hbuf, fc1b, DMODEL, DMODEL, DMODEL, DFF);

  // 11. out = x1 + h fc2_w^T + fc2_b  (fp32)
  //     128x128 dbuf (2 blocks/CU, 17.8 B/cyc) + NSWAP, grid 64x8
  {
    dim3 g(NROWS / 128, DMODEL / 128, 1);
    gemm_bt<true,true,false,true,false,false,false,true><<<g, 256, 0, stream>>>(
        hbuf, 0, fc2w_b, 0, out, 0, fc2b, x1, 0, DFF, DFF, DFF, DMODEL, 1.f);
  }
}

// Round 6
// 508.931 us; speedup vs baseline: 1.0079x; 1.0079x over previous
//
#include <hip/hip_runtime.h>

// ---------------------------------------------------------------------------
// DecoderLayer forward: B=4, S=2048, D=1024, F=4096, single-head causal attn.
// Round 19. r18 answered the NSWAP probe: 3.4x more L2-miss traffic, ~0 time
// delta -> the staging cap is the CU's global_load_lds path, not the fabric.
// NSWAP reverted everywhere. New: FC2 moves to a TRI-BUFFER 256x128 kernel
// (144 KB LDS, 8 waves). With 3 buffers, stage(it+2) can be issued MID-
// compute(it) (target buf != read buf; all waves passed REL(it-1) via
// ACQ(it)) -> DMA always has >=1.5 stages queued, the depth-1 idle tail
// disappears. m201 evidence: this schedule family sustains ~22 B/cyc/CU at
// 1 block/CU. FC2 staged = 768 MB = 3 MB/CU -> 57-70us (from 97.9).
// QKV/FC1 keep r16's 256x256 counted-vmcnt dbuf; scores/PV/Wo keep 128x128.
// ---------------------------------------------------------------------------

typedef __attribute__((ext_vector_type(8))) short short8;   // 8 x bf16 (4 VGPR)
typedef __attribute__((ext_vector_type(4))) float f32x4;    // MFMA C/D

#define DMODEL 1024
#define DFF    4096
#define NB     4
#define SEQ    2048
#define NROWS  (NB * SEQ)   // 8192
#define QKVN   (3 * DMODEL) // 3072

__device__ __forceinline__ unsigned short f2bf(float f) {
  union { float f; unsigned u; } v; v.f = f;
  unsigned r = v.u + 0x7FFFu + ((v.u >> 16) & 1u);  // round-to-nearest-even
  return (unsigned short)(r >> 16);
}
__device__ __forceinline__ float bf2f(unsigned short h) {
  union { unsigned u; float f; } v; v.u = ((unsigned)h) << 16;
  return v.f;
}

// async global -> LDS, 16 bytes per lane; lds base must be wave-uniform,
// lane i's data lands at lds + i*16 (m104/m108 constraint).
__device__ __forceinline__ void g2l16(const unsigned short* g, unsigned short* lds) {
  __builtin_amdgcn_global_load_lds(
      (const __attribute__((address_space(1))) void*)g,
      (__attribute__((address_space(3))) void*)lds,
      16, 0, 0);
}

// barrier-entry fence: all waves' current-tile staging visible, and no LDS
// read may be scheduled between the per-wave wait and the barrier.
#define BAR_ACQ() do {                         \
    __builtin_amdgcn_s_barrier();              \
    asm volatile("" ::: "memory");             \
    __builtin_amdgcn_sched_barrier(0);         \
  } while (0)
// barrier-exit fence: compute's LDS reads may not sink past the barrier into
// the stage region that overwrites the buffer.
#define BAR_REL() do {                         \
    __builtin_amdgcn_sched_barrier(0);         \
    asm volatile("" ::: "memory");             \
    __builtin_amdgcn_s_barrier();              \
  } while (0)

// ---- fp32 -> bf16 convert, all 6 weight tensors in one launch ----
__global__ __launch_bounds__(256) void cvt_bf16_all(
    const float* __restrict__ s0, const float* __restrict__ s1,
    const float* __restrict__ s2, const float* __restrict__ s3,
    const float* __restrict__ s4, const float* __restrict__ s5,
    unsigned short* __restrict__ d0, unsigned short* __restrict__ d1,
    unsigned short* __restrict__ d2, unsigned short* __restrict__ d3,
    unsigned short* __restrict__ d4, unsigned short* __restrict__ d5,
    int n_small, int n_big) {
  const int z = blockIdx.y;
  const float* src; unsigned short* dst; int n4;
  switch (z) {
    case 0: src = s0; dst = d0; n4 = n_small; break;
    case 1: src = s1; dst = d1; n4 = n_small; break;
    case 2: src = s2; dst = d2; n4 = n_small; break;
    case 3: src = s3; dst = d3; n4 = n_small; break;
    case 4: src = s4; dst = d4; n4 = n_big;   break;
    default: src = s5; dst = d5; n4 = n_big;  break;
  }
  int i = blockIdx.x * 256 + threadIdx.x;
  if (i >= n4) return;
  float4 v = reinterpret_cast<const float4*>(src)[i];
  ushort4 o;
  o.x = f2bf(v.x); o.y = f2bf(v.y); o.z = f2bf(v.z); o.w = f2bf(v.w);
  reinterpret_cast<ushort4*>(dst)[i] = o;
}

// ---- LayerNorm over D=1024, one 256-thread block per row, bf16 out ----
__global__ __launch_bounds__(256) void ln_bf16(const float* __restrict__ x,
                                               const float* __restrict__ g,
                                               const float* __restrict__ b,
                                               unsigned short* __restrict__ out) {
  int row = blockIdx.x;
  int t = threadIdx.x;
  const float* xr = x + (size_t)row * DMODEL;
  float4 v = reinterpret_cast<const float4*>(xr)[t];
  float s  = v.x + v.y + v.z + v.w;
  float s2 = v.x*v.x + v.y*v.y + v.z*v.z + v.w*v.w;
  #pragma unroll
  for (int off = 32; off > 0; off >>= 1) {
    s  += __shfl_down(s, off);
    s2 += __shfl_down(s2, off);
  }
  __shared__ float rs[4], rs2[4], stats[2];
  int lane = t & 63, wave = t >> 6;
  if (lane == 0) { rs[wave] = s; rs2[wave] = s2; }
  __syncthreads();
  if (t == 0) {
    float ts  = rs[0] + rs[1] + rs[2] + rs[3];
    float ts2 = rs2[0] + rs2[1] + rs2[2] + rs2[3];
    float mu = ts / DMODEL;
    stats[0] = mu;
    stats[1] = rsqrtf(ts2 / DMODEL - mu * mu + 1e-5f);
  }
  __syncthreads();
  float mu = stats[0], rstd = stats[1];
  float4 gg = reinterpret_cast<const float4*>(g)[t];
  float4 bb = reinterpret_cast<const float4*>(b)[t];
  ushort4 o;
  o.x = f2bf((v.x - mu) * rstd * gg.x + bb.x);
  o.y = f2bf((v.y - mu) * rstd * gg.y + bb.y);
  o.z = f2bf((v.z - mu) * rstd * gg.z + bb.z);
  o.w = f2bf((v.w - mu) * rstd * gg.w + bb.w);
  reinterpret_cast<ushort4*>(out + (size_t)row * DMODEL)[t] = o;
}

// ---- bf16 tile transpose: in [R][C] (row stride ldin) -> out [C][R] ----
__global__ __launch_bounds__(256) void transpose_bf16(const unsigned short* __restrict__ in,
                                                      unsigned short* __restrict__ out,
                                                      int R, int C, int ldin,
                                                      size_t sIn, size_t sOut) {
  __shared__ unsigned short tile[32][33];
  in  += (size_t)blockIdx.z * sIn;
  out += (size_t)blockIdx.z * sOut;
  int c0 = blockIdx.x * 32, r0 = blockIdx.y * 32;
  int tx = threadIdx.x & 31, ty = threadIdx.x >> 5;  // 32 x 8
  #pragma unroll
  for (int i = 0; i < 4; ++i)
    tile[ty + i * 8][tx] = in[(size_t)(r0 + ty + i * 8) * ldin + c0 + tx];
  __syncthreads();
  #pragma unroll
  for (int i = 0; i < 4; ++i)
    out[(size_t)(c0 + ty + i * 8) * R + r0 + tx] = tile[tx][ty + i * 8];
}

// ---- causal row softmax: bf16 scores -> bf16 probs; writes only the
// k-range PV will read (k < ceil((q+1)/128)*128) ----
__global__ __launch_bounds__(256) void softmax_causal(const unsigned short* __restrict__ Sc,
                                                      unsigned short* __restrict__ P) {
  const int q = blockIdx.x, b = blockIdx.y;
  const unsigned short* srow = Sc + ((size_t)b * SEQ + q) * SEQ;
  unsigned short* prow = P + ((size_t)b * SEQ + q) * SEQ;
  const int L = q + 1;
  const int kcap = (q & ~127) + 128;   // PV reads k < m0+128 = kcap for row q
  const int t = threadIdx.x;
  __shared__ float red[4];
  __shared__ float bc;

  float mx = -1e30f;
  for (int i = t; i < L; i += 256) mx = fmaxf(mx, bf2f(srow[i]));
  #pragma unroll
  for (int off = 32; off > 0; off >>= 1) mx = fmaxf(mx, __shfl_down(mx, off));
  if ((t & 63) == 0) red[t >> 6] = mx;
  __syncthreads();
  if (t == 0) bc = fmaxf(fmaxf(red[0], red[1]), fmaxf(red[2], red[3]));
  __syncthreads();
  mx = bc;

  float sum = 0.f;
  for (int i = t; i < L; i += 256) sum += __expf(bf2f(srow[i]) - mx);
  #pragma unroll
  for (int off = 32; off > 0; off >>= 1) sum += __shfl_down(sum, off);
  __syncthreads();            // red reuse guard
  if ((t & 63) == 0) red[t >> 6] = sum;
  __syncthreads();
  if (t == 0) bc = 1.0f / (red[0] + red[1] + red[2] + red[3]);
  __syncthreads();
  float inv = bc;

  for (int i = t; i < kcap; i += 256) {
    float p = (i < L) ? __expf(bf2f(srow[i]) - mx) * inv : 0.f;
    prow[i] = f2bf(p);
  }
}

// ---------------------------------------------------------------------------
// 128x128 GEMM (scores / PV / Wo): 4 waves (2x2 of 64x64), BK=64,
// dbuf LDS, 1 barrier/iter, global_load_lds width=16, XOR swizzle (0 bank
// conflicts), 8x8 super-tile remap; 2 blocks/CU cover the __syncthreads
// vmcnt drain (17.8 B/cyc measured). (r16 kernel, NSWAP removed.)
// ---------------------------------------------------------------------------
template<bool OUT_F32, bool ADD_BIAS, bool RELU, bool ADD_RESID,
         bool CAUSAL_SKIP, bool CAUSAL_KLIM, bool SCALE>
__global__ __launch_bounds__(256) void gemm_bt(
    const unsigned short* __restrict__ A, size_t sA,
    const unsigned short* __restrict__ B, size_t sB,
    void* __restrict__ Cv, size_t sC,
    const float* __restrict__ bias,
    const float* __restrict__ resid, size_t sR,
    int K, int lda, int ldb, int ldc, float scale) {
  const int GX = gridDim.x;                    // m-blocks (multiple of 8)
  const int linear = blockIdx.y * GX + blockIdx.x;
  const int tileId = linear >> 6;
  const int within = linear & 63;
  const int mGroups = GX >> 3;
  const int m_blk = (tileId % mGroups) * 8 + (within & 7);
  const int n_blk = (tileId / mGroups) * 8 + (within >> 3);
  const int m0 = m_blk * 128;
  const int n0 = n_blk * 128;
  if (CAUSAL_SKIP && n0 > m0 + 127) return;  // block fully masked
  const int bz = blockIdx.z;
  A += (size_t)bz * sA;
  B += (size_t)bz * sB;

  __shared__ unsigned short As[2][128 * 64];   // 2 x 16 KB, XOR-swizzled
  __shared__ unsigned short Bs[2][128 * 64];

  const int t = threadIdx.x;
  const int lane = t & 63;
  const int wave = t >> 6;
  const int wm = (wave >> 1) * 64;
  const int wn = (wave & 1) * 64;
  const int lr = lane & 15;
  const int lq = lane >> 4;

  const int srow = lane >> 3;                  // 0..7
  const int pcol = ((lane & 7) ^ srow) * 8;    // XOR-swizzled fetch col

  f32x4 acc[4][4] = {};

  const int kEnd  = CAUSAL_KLIM ? min(K, m0 + 128) : K;
  const int nIter = kEnd >> 6;                 // BK = 64

  auto stage = [&](int buf, int kt) {
    #pragma unroll
    for (int i = 0; i < 4; ++i) {
      const int c = wave * 4 + i;              // chunk 0..15
      const int row = c * 8 + srow;
      g2l16(&A[(size_t)(m0 + row) * lda + kt + pcol], &As[buf][c * 512]);
      g2l16(&B[(size_t)(n0 + row) * ldb + kt + pcol], &Bs[buf][c * 512]);
    }
  };

  stage(0, 0);

  for (int it = 0; it < nIter; ++it) {
    __syncthreads();   // drains vmcnt: buf[it&1] ready; other free to fill
    if (it + 1 < nIter) stage((it + 1) & 1, (it + 1) << 6);
    const unsigned short* Ab = As[it & 1];
    const unsigned short* Bb = Bs[it & 1];
    #pragma unroll
    for (int kk = 0; kk < 2; ++kk) {
      short8 af[4], bfr[4];
      #pragma unroll
      for (int i = 0; i < 4; ++i) {
        const int r = wm + i * 16 + lr;
        af[i] = *reinterpret_cast<const short8*>(
            &Ab[r * 64 + (((kk * 4 + lq) ^ (r & 7)) * 8)]);
      }
      #pragma unroll
      for (int j = 0; j < 4; ++j) {
        const int r = wn + j * 16 + lr;
        bfr[j] = *reinterpret_cast<const short8*>(
            &Bb[r * 64 + (((kk * 4 + lq) ^ (r & 7)) * 8)]);
      }
      #pragma unroll
      for (int i = 0; i < 4; ++i)
        #pragma unroll
        for (int j = 0; j < 4; ++j)
          acc[i][j] = __builtin_amdgcn_mfma_f32_16x16x32_bf16(af[i], bfr[j], acc[i][j], 0, 0, 0);
    }
  }

  float* Cf = (float*)Cv + (size_t)bz * sC;
  unsigned short* Ch = (unsigned short*)Cv + (size_t)bz * sC;
  const float* rr = ADD_RESID ? (resid + (size_t)bz * sR) : nullptr;
  #pragma unroll
  for (int i = 0; i < 4; ++i) {
    #pragma unroll
    for (int j = 0; j < 4; ++j) {
      #pragma unroll
      for (int r = 0; r < 4; ++r) {
        // C/D layout (verified m89/m91): col = lane&15, row = (lane>>4)*4 + reg
        int row = m0 + wm + i * 16 + lq * 4 + r;
        int col = n0 + wn + j * 16 + lr;
        float v = acc[i][j][r];
        if (SCALE)     v *= scale;
        if (ADD_BIAS)  v += bias[col];
        if (RELU)      v = fmaxf(v, 0.0f);
        if (ADD_RESID) v += rr[(size_t)row * ldc + col];
        if (OUT_F32) Cf[(size_t)row * ldc + col] = v;
        else         Ch[(size_t)row * ldc + col] = f2bf(v);
      }
    }
  }
}

// ---------------------------------------------------------------------------
// 256x256 GEMM (FC1 / QKV): 1024 threads = 16 waves (4x4 of 64x64), BK=64,
// dbuf 128 KB LDS, counted-vmcnt pipeline (per-wave 4 loads/stage, wait
// vmcnt(4) leaves the next stage in flight across both raw barriers).
// (r16 kernel, NSWAP removed: 8x8 supertile when GY%8==0, else identity.)
// ---------------------------------------------------------------------------
template<bool OUT_F32, bool ADD_BIAS, bool RELU>
__global__ __launch_bounds__(1024) void gemm_bt256(
    const unsigned short* __restrict__ A,
    const unsigned short* __restrict__ B,
    void* __restrict__ Cv,
    const float* __restrict__ bias,
    int K, int lda, int ldb, int ldc) {
  int m_blk, n_blk;
  if ((gridDim.y & 7) == 0) {                  // 8x8 super-tile remap
    const int GX = gridDim.x;
    const int linear = blockIdx.y * GX + blockIdx.x;
    const int tileId = linear >> 6;
    const int within = linear & 63;
    const int mGroups = GX >> 3;
    m_blk = (tileId % mGroups) * 8 + (within & 7);
    n_blk = (tileId / mGroups) * 8 + (within >> 3);
  } else {                                     // identity (e.g. QKV GY=12)
    m_blk = blockIdx.x;
    n_blk = blockIdx.y;
  }
  const int m0 = m_blk * 256;
  const int n0 = n_blk * 256;

  __shared__ unsigned short As[2][256 * 64];   // 2 x 32 KB, XOR-swizzled
  __shared__ unsigned short Bs[2][256 * 64];   // 2 x 32 KB  (128 KB total)

  const int t = threadIdx.x;
  const int lane = t & 63;
  const int wave = t >> 6;                     // 0..15
  const int wm = (wave >> 2) * 64;             // 0,64,128,192
  const int wn = (wave & 3) * 64;              // 0,64,128,192
  const int lr = lane & 15;
  const int lq = lane >> 4;

  const int srow = lane >> 3;                  // 0..7
  const int pcol = ((lane & 7) ^ srow) * 8;    // XOR-swizzled fetch col

  f32x4 acc[4][4] = {};
  const int nIter = K >> 6;                    // BK = 64 (nIter >= 2 here)

  auto stage = [&](int buf, int kt) {
    #pragma unroll
    for (int i = 0; i < 2; ++i) {
      const int c = wave * 2 + i;              // chunk 0..31
      const int row = c * 8 + srow;
      g2l16(&A[(size_t)(m0 + row) * lda + kt + pcol], &As[buf][c * 512]);
      g2l16(&B[(size_t)(n0 + row) * ldb + kt + pcol], &Bs[buf][c * 512]);
    }
  };

  stage(0, 0);        // 4 loads/wave
  stage(1, 64);       // 4 more -> 8 outstanding/wave

  for (int it = 0; it < nIter; ++it) {
    // own stage(it) complete; stage(it+1)'s 4 loads may remain in flight
    if (it + 1 < nIter) asm volatile("s_waitcnt vmcnt(4)" ::: "memory");
    else                asm volatile("s_waitcnt vmcnt(0)" ::: "memory");
    BAR_ACQ();         // all waves' stage(it) complete
    const unsigned short* Ab = As[it & 1];
    const unsigned short* Bb = Bs[it & 1];
    #pragma unroll
    for (int kk = 0; kk < 2; ++kk) {
      short8 af[4], bfr[4];
      #pragma unroll
      for (int i = 0; i < 4; ++i) {
        const int r = wm + i * 16 + lr;
        af[i] = *reinterpret_cast<const short8*>(
            &Ab[r * 64 + (((kk * 4 + lq) ^ (r & 7)) * 8)]);
      }
      #pragma unroll
      for (int j = 0; j < 4; ++j) {
        const int r = wn + j * 16 + lr;
        bfr[j] = *reinterpret_cast<const short8*>(
            &Bb[r * 64 + (((kk * 4 + lq) ^ (r & 7)) * 8)]);
      }
      #pragma unroll
      for (int i = 0; i < 4; ++i)
        #pragma unroll
        for (int j = 0; j < 4; ++j)
          acc[i][j] = __builtin_amdgcn_mfma_f32_16x16x32_bf16(af[i], bfr[j], acc[i][j], 0, 0, 0);
    }
    BAR_REL();         // all waves done reading buf[it&1]
    if (it + 2 < nIter) stage(it & 1, (it + 2) << 6);
  }

  float* Cf = (float*)Cv;
  unsigned short* Ch = (unsigned short*)Cv;
  #pragma unroll
  for (int i = 0; i < 4; ++i) {
    #pragma unroll
    for (int j = 0; j < 4; ++j) {
      #pragma unroll
      for (int r = 0; r < 4; ++r) {
        int row = m0 + wm + i * 16 + lq * 4 + r;
        int col = n0 + wn + j * 16 + lr;
        float v = acc[i][j][r];
        if (ADD_BIAS) v += bias[col];
        if (RELU)     v = fmaxf(v, 0.0f);
        if (OUT_F32) Cf[(size_t)row * ldc + col] = v;
        else         Ch[(size_t)row * ldc + col] = f2bf(v);
      }
    }
  }
}

// ---------------------------------------------------------------------------
// 256x128 TRI-BUFFER GEMM (FC2): 512 threads = 8 waves (4x2 of 64x64), BK=64,
// 3 LDS buffers (144 KB), counted vmcnt, stage(it+2) issued MID-compute(it):
//   wait vmcnt(6); ACQ; kk=0 MFMAs; stage(it+2)->buf[(it+2)%3]; kk=1; REL
// Hazard: (it+2)%3 != it%3 (read buf); buffer (it+2)%3 was last read in
// compute(it-1), and ACQ(it) orders all waves past REL(it-1) before any
// issues the stage. DMA always holds >=1.5 stages -> no idle tail (m201
// mechanism). Grid 32x8 = 256 = 1 block/CU; staged 3 MB/CU.
// ---------------------------------------------------------------------------
template<bool OUT_F32, bool ADD_BIAS, bool RELU, bool ADD_RESID>
__global__ __launch_bounds__(512) void gemm_tri(
    const unsigned short* __restrict__ A,
    const unsigned short* __restrict__ B,
    void* __restrict__ Cv,
    const float* __restrict__ bias,
    const float* __restrict__ resid,
    int K, int lda, int ldb, int ldc) {
  const int GX = gridDim.x;                    // m-blocks (multiple of 8)
  const int linear = blockIdx.y * GX + blockIdx.x;
  const int tileId = linear >> 6;
  const int within = linear & 63;
  const int mGroups = GX >> 3;
  const int m_blk = (tileId % mGroups) * 8 + (within & 7);
  const int n_blk = (tileId / mGroups) * 8 + (within >> 3);
  const int m0 = m_blk * 256;
  const int n0 = n_blk * 128;

  __shared__ unsigned short As[3][256 * 64];   // 3 x 32 KB
  __shared__ unsigned short Bs[3][128 * 64];   // 3 x 16 KB  (144 KB total)

  const int t = threadIdx.x;
  const int lane = t & 63;
  const int wave = t >> 6;                     // 0..7
  const int wm = (wave >> 1) * 64;             // 0,64,128,192
  const int wn = (wave & 1) * 64;              // 0,64
  const int lr = lane & 15;
  const int lq = lane >> 4;

  const int srow = lane >> 3;                  // 0..7
  const int pcol = ((lane & 7) ^ srow) * 8;    // XOR-swizzled fetch col

  f32x4 acc[4][4] = {};
  const int nIter = K >> 6;                    // BK = 64 (FC2: 64 iters)

  auto stage = [&](int buf, int kt) {
    #pragma unroll
    for (int i = 0; i < 4; ++i) {              // A: 32 chunks / 8 waves
      const int c = wave * 4 + i;
      const int row = c * 8 + srow;
      g2l16(&A[(size_t)(m0 + row) * lda + kt + pcol], &As[buf][c * 512]);
    }
    #pragma unroll
    for (int i = 0; i < 2; ++i) {              // B: 16 chunks / 8 waves
      const int c = wave * 2 + i;
      const int row = c * 8 + srow;
      g2l16(&B[(size_t)(n0 + row) * ldb + kt + pcol], &Bs[buf][c * 512]);
    }
  };

  stage(0, 0);        // 6 loads/wave
  stage(1, 64);       // 6 more -> 12 outstanding/wave

  int cur = 0;
  for (int it = 0; it < nIter; ++it) {
    // wait for own stage(it); stage(it+1) (and later stage(it+2)) stay in flight
    if (it + 1 < nIter) asm volatile("s_waitcnt vmcnt(6)" ::: "memory");
    else                asm volatile("s_waitcnt vmcnt(0)" ::: "memory");
    BAR_ACQ();         // all waves' stage(it) complete; all done reading buf[(it-1)%3]
    const unsigned short* Ab = As[cur];
    const unsigned short* Bb = Bs[cur];

    // ---- kk = 0 ----
    {
      short8 af[4], bfr[4];
      #pragma unroll
      for (int i = 0; i < 4; ++i) {
        const int r = wm + i * 16 + lr;
        af[i] = *reinterpret_cast<const short8*>(
            &Ab[r * 64 + ((lq ^ (r & 7)) * 8)]);
      }
      #pragma unroll
      for (int j = 0; j < 4; ++j) {
        const int r = wn + j * 16 + lr;
        bfr[j] = *reinterpret_cast<const short8*>(
            &Bb[r * 64 + ((lq ^ (r & 7)) * 8)]);
      }
      #pragma unroll
      for (int i = 0; i < 4; ++i)
        #pragma unroll
        for (int j = 0; j < 4; ++j)
          acc[i][j] = __builtin_amdgcn_mfma_f32_16x16x32_bf16(af[i], bfr[j], acc[i][j], 0, 0, 0);
    }

    // ---- mid-compute: issue stage(it+2) into buf (cur+2)%3 (!= cur) ----
    if (it + 2 < nIter) {
      int b2 = cur + 2; if (b2 >= 3) b2 -= 3;
      stage(b2, (it + 2) << 6);
    }

    // ---- kk = 1 ----
    {
      short8 af[4], bfr[4];
      #pragma unroll
      for (int i = 0; i < 4; ++i) {
        const int r = wm + i * 16 + lr;
        af[i] = *reinterpret_cast<const short8*>(
            &Ab[r * 64 + (((4 + lq) ^ (r & 7)) * 8)]);
      }
      #pragma unroll
      for (int j = 0; j < 4; ++j) {
        const int r = wn + j * 16 + lr;
        bfr[j] = *reinterpret_cast<const short8*>(
            &Bb[r * 64 + (((4 + lq) ^ (r & 7)) * 8)]);
      }
      #pragma unroll
      for (int i = 0; i < 4; ++i)
        #pragma unroll
        for (int j = 0; j < 4; ++j)
          acc[i][j] = __builtin_amdgcn_mfma_f32_16x16x32_bf16(af[i], bfr[j], acc[i][j], 0, 0, 0);
    }

    BAR_REL();         // all waves done reading buf[cur]
    cur = (cur + 1 == 3) ? 0 : cur + 1;
  }

  float* Cf = (float*)Cv;
  unsigned short* Ch = (unsigned short*)Cv;
  #pragma unroll
  for (int i = 0; i < 4; ++i) {
    #pragma unroll
    for (int j = 0; j < 4; ++j) {
      #pragma unroll
      for (int r = 0; r < 4; ++r) {
        int row = m0 + wm + i * 16 + lq * 4 + r;
        int col = n0 + wn + j * 16 + lr;
        float v = acc[i][j][r];
        if (ADD_BIAS)  v += bias[col];
        if (RELU)      v = fmaxf(v, 0.0f);
        if (ADD_RESID) v += resid[(size_t)row * ldc + col];
        if (OUT_F32) Cf[(size_t)row * ldc + col] = v;
        else         Ch[(size_t)row * ldc + col] = f2bf(v);
      }
    }
  }
}

// ---------------------------------------------------------------------------
extern "C" void kernel_launch(void* const* d_in, const int* in_sizes, int n_in,
                              void* d_out, int out_size, void* d_ws, size_t ws_size,
                              hipStream_t stream) {
  const float* x    = (const float*)d_in[0];
  const float* Wq   = (const float*)d_in[1];
  const float* Wk   = (const float*)d_in[2];
  const float* Wv   = (const float*)d_in[3];
  const float* Wo   = (const float*)d_in[4];
  const float* fc1w = (const float*)d_in[5];
  const float* fc1b = (const float*)d_in[6];
  const float* fc2w = (const float*)d_in[7];
  const float* fc2b = (const float*)d_in[8];
  const float* ln1g = (const float*)d_in[9];
  const float* ln1b = (const float*)d_in[10];
  const float* ln2g = (const float*)d_in[11];
  const float* ln2b = (const float*)d_in[12];
  float* out = (float*)d_out;

  // workspace carve-up with liveness aliasing
  char* w = (char*)d_ws;
  auto alloc = [&](size_t bytes) {
    char* p = w;
    w += (bytes + 255) & ~(size_t)255;
    return p;
  };
  typedef unsigned short u16;
  u16* wqkv_b = (u16*)alloc((size_t)QKVN * DMODEL * 2);   // stacked Q|K|V
  u16* wq_b   = wqkv_b;
  u16* wk_b   = wqkv_b + (size_t)DMODEL * DMODEL;
  u16* wv_b   = wqkv_b + (size_t)2 * DMODEL * DMODEL;
  u16* wo_b   = (u16*)alloc((size_t)DMODEL * DMODEL * 2);
  u16* fc1w_b = (u16*)alloc((size_t)DFF * DMODEL * 2);
  u16* fc2w_b = (u16*)alloc((size_t)DMODEL * DFF * 2);
  u16* xn     = (u16*)alloc((size_t)NROWS * DMODEL * 2);
  u16* qkv    = (u16*)alloc((size_t)NROWS * QKVN * 2);    // 48 MB
  u16* vt     = (u16*)alloc((size_t)NROWS * DMODEL * 2);
  u16* ctx    = (u16*)alloc((size_t)NROWS * DMODEL * 2);
  u16* xn2    = (u16*)alloc((size_t)NROWS * DMODEL * 2);
  // Region A (64 MB): sc_h (bf16 scores, steps 5-6) aliased with hbuf (10-11)
  char* regA  = (char*)alloc((size_t)NB * SEQ * SEQ * 4);
  u16*   sc_h = (u16*)regA;
  u16*   hbuf = (u16*)regA;
  // Region B (32 MB): Pbuf (steps 6-7) aliased with x1 (steps 8-11)
  char* regB  = (char*)alloc((size_t)NB * SEQ * SEQ * 2);
  u16*   Pbuf = (u16*)regB;
  float* x1   = (float*)regB;

  // 1. weights -> bf16 (single launch; z selects tensor)
  {
    int n_small = DMODEL * DMODEL / 4;
    int n_big   = DFF * DMODEL / 4;
    dim3 g((n_big + 255) / 256, 6);
    cvt_bf16_all<<<g, 256, 0, stream>>>(Wq, Wk, Wv, Wo, fc1w, fc2w,
                                        wq_b, wk_b, wv_b, wo_b, fc1w_b, fc2w_b,
                                        n_small, n_big);
  }

  // 2. LN1
  ln_bf16<<<dim3(NROWS), 256, 0, stream>>>(x, ln1g, ln1b, xn);

  // 3. merged QKV projection: [8192,1024] x [3072,1024]^T -> qkv [8192,3072]
  //    256x256 dbuf counted-vmcnt, grid 32x12 = 384 blocks (identity map)
  gemm_bt256<false,false,false><<<dim3(NROWS / 256, QKVN / 256), 1024, 0, stream>>>(
      xn, wqkv_b, qkv, nullptr, DMODEL, DMODEL, DMODEL, QKVN);
  const u16* qb = qkv;                 // lda = QKVN
  const u16* kb = qkv + DMODEL;
  const u16* vb = qkv + 2 * DMODEL;

  // 4. V^T per batch: [2048,1024] (stride 3072) -> [1024,2048]
  transpose_bf16<<<dim3(DMODEL / 32, SEQ / 32, NB), 256, 0, stream>>>(
      vb, vt, SEQ, DMODEL, QKVN, (size_t)SEQ * QKVN, (size_t)DMODEL * SEQ);

  // 5. scores = Q K^T / sqrt(D), bf16 out, skip fully-masked blocks
  {
    dim3 g(SEQ / 128, SEQ / 128, NB);
    gemm_bt<false,false,false,false,true,false,true><<<g, 256, 0, stream>>>(
        qb, (size_t)SEQ * QKVN, kb, (size_t)SEQ * QKVN, sc_h, (size_t)SEQ * SEQ,
        nullptr, nullptr, 0, DMODEL, QKVN, QKVN, SEQ, 0.03125f /*1/sqrt(1024)*/);
  }

  // 6. causal softmax (bf16 in/out; writes only k < ceil((q+1)/128)*128)
  softmax_causal<<<dim3(SEQ, NB), 256, 0, stream>>>(sc_h, Pbuf);

  // 7. ctx = P V  (K-reduction bounded by causality)
  {
    dim3 g(SEQ / 128, DMODEL / 128, NB);
    gemm_bt<false,false,false,false,false,true,false><<<g, 256, 0, stream>>>(
        Pbuf, (size_t)SEQ * SEQ, vt, (size_t)DMODEL * SEQ, ctx, (size_t)SEQ * DMODEL,
        nullptr, nullptr, 0, SEQ, SEQ, SEQ, DMODEL, 1.f);
  }

  // 8. x1 = x + ctx Wo^T  (fp32)  -- x1 aliases Pbuf (dead after step 7)
  {
    dim3 g(NROWS / 128, DMODEL / 128, 1);
    gemm_bt<true,false,false,true,false,false,false><<<g, 256, 0, stream>>>(
        ctx, 0, wo_b, 0, x1, 0, nullptr, x, 0, DMODEL, DMODEL, DMODEL, DMODEL, 1.f);
  }

  // 9. LN2
  ln_bf16<<<dim3(NROWS), 256, 0, stream>>>(x1, ln2g, ln2b, xn2);

  // 10. h = relu(xn2 fc1_w^T + fc1_b)  bf16 [8192,4096]
  //     256x256 dbuf counted-vmcnt, grid 32x16 = 512 blocks
  gemm_bt256<false,true,true><<<dim3(NROWS / 256, DFF / 256), 1024, 0, stream>>>(
      xn2, fc1w_b, hbuf, fc1b, DMODEL, DMODEL, DMODEL, DFF);

  // 11. out = x1 + h fc2_w^T + fc2_b  (fp32)
  //     256x128 TRI-BUFFER mid-issue, grid 32x8 = 256 = 1 block/CU
  gemm_tri<true,true,false,true><<<dim3(NROWS / 256, DMODEL / 128), 512, 0, stream>>>(
      hbuf, fc2w_b, out, fc2b, x1, DFF, DFF, DFF, DMODEL);
}

// Round 7
// 497.680 us; speedup vs baseline: 1.0307x; 1.0226x over previous
//
#include <hip/hip_runtime.h>

// ---------------------------------------------------------------------------
// DecoderLayer forward: B=4, S=2048, D=1024, F=4096, single-head causal attn.
// Round 20. r19 post-mortem: tri-buffer (stage it+2 mid-compute) == dbuf
// counted (104.5 vs 108.6) -> a single block's global_load_lds stream caps
// ~12 B/cyc no matter the queue depth; 2 co-resident blocks reach 17.8.
// Model: per-block-stream cap ~12, streams add sub-linearly. The 2-block
// 128x128 config still drains each block's queue at every __syncthreads
// (vmcnt(0)) -> measured 17.8 not ~24. This round: port the PROVEN r16
// counted-vmcnt dbuf skeleton (gemm_bt256's exact pattern) into the 128x128
// kernel so both resident blocks keep their queues fed continuously:
//   prologue stage(0),stage(1); loop { wait vmcnt(8); ACQ; MFMA; REL;
//   stage(it+2) }  -- never drains mid-loop.
// FC2 reverts to this 128x128 kernel (grid 64x8, 2 blocks/CU); gemm_tri
// dropped. scores/PV/Wo get the same upgrade for free. QKV/FC1 keep the
// r16 256x256 counted-dbuf kernel.
// Prediction: if streams add, FC2 97.9 -> ~72us; if 17.8 is a CU cap,
// ~90-98. Either beats r19's 104.5 and pins the scaling law.
// ---------------------------------------------------------------------------

typedef __attribute__((ext_vector_type(8))) short short8;   // 8 x bf16 (4 VGPR)
typedef __attribute__((ext_vector_type(4))) float f32x4;    // MFMA C/D

#define DMODEL 1024
#define DFF    4096
#define NB     4
#define SEQ    2048
#define NROWS  (NB * SEQ)   // 8192
#define QKVN   (3 * DMODEL) // 3072

__device__ __forceinline__ unsigned short f2bf(float f) {
  union { float f; unsigned u; } v; v.f = f;
  unsigned r = v.u + 0x7FFFu + ((v.u >> 16) & 1u);  // round-to-nearest-even
  return (unsigned short)(r >> 16);
}
__device__ __forceinline__ float bf2f(unsigned short h) {
  union { unsigned u; float f; } v; v.u = ((unsigned)h) << 16;
  return v.f;
}

// async global -> LDS, 16 bytes per lane; lds base must be wave-uniform,
// lane i's data lands at lds + i*16 (m104/m108 constraint).
__device__ __forceinline__ void g2l16(const unsigned short* g, unsigned short* lds) {
  __builtin_amdgcn_global_load_lds(
      (const __attribute__((address_space(1))) void*)g,
      (__attribute__((address_space(3))) void*)lds,
      16, 0, 0);
}

// barrier-entry fence: all waves' current-tile staging visible, and no LDS
// read may be scheduled between the per-wave wait and the barrier.
#define BAR_ACQ() do {                         \
    __builtin_amdgcn_s_barrier();              \
    asm volatile("" ::: "memory");             \
    __builtin_amdgcn_sched_barrier(0);         \
  } while (0)
// barrier-exit fence: compute's LDS reads may not sink past the barrier into
// the stage region that overwrites the buffer.
#define BAR_REL() do {                         \
    __builtin_amdgcn_sched_barrier(0);         \
    asm volatile("" ::: "memory");             \
    __builtin_amdgcn_s_barrier();              \
  } while (0)

// ---- fp32 -> bf16 convert, all 6 weight tensors in one launch ----
__global__ __launch_bounds__(256) void cvt_bf16_all(
    const float* __restrict__ s0, const float* __restrict__ s1,
    const float* __restrict__ s2, const float* __restrict__ s3,
    const float* __restrict__ s4, const float* __restrict__ s5,
    unsigned short* __restrict__ d0, unsigned short* __restrict__ d1,
    unsigned short* __restrict__ d2, unsigned short* __restrict__ d3,
    unsigned short* __restrict__ d4, unsigned short* __restrict__ d5,
    int n_small, int n_big) {
  const int z = blockIdx.y;
  const float* src; unsigned short* dst; int n4;
  switch (z) {
    case 0: src = s0; dst = d0; n4 = n_small; break;
    case 1: src = s1; dst = d1; n4 = n_small; break;
    case 2: src = s2; dst = d2; n4 = n_small; break;
    case 3: src = s3; dst = d3; n4 = n_small; break;
    case 4: src = s4; dst = d4; n4 = n_big;   break;
    default: src = s5; dst = d5; n4 = n_big;  break;
  }
  int i = blockIdx.x * 256 + threadIdx.x;
  if (i >= n4) return;
  float4 v = reinterpret_cast<const float4*>(src)[i];
  ushort4 o;
  o.x = f2bf(v.x); o.y = f2bf(v.y); o.z = f2bf(v.z); o.w = f2bf(v.w);
  reinterpret_cast<ushort4*>(dst)[i] = o;
}

// ---- LayerNorm over D=1024, one 256-thread block per row, bf16 out ----
__global__ __launch_bounds__(256) void ln_bf16(const float* __restrict__ x,
                                               const float* __restrict__ g,
                                               const float* __restrict__ b,
                                               unsigned short* __restrict__ out) {
  int row = blockIdx.x;
  int t = threadIdx.x;
  const float* xr = x + (size_t)row * DMODEL;
  float4 v = reinterpret_cast<const float4*>(xr)[t];
  float s  = v.x + v.y + v.z + v.w;
  float s2 = v.x*v.x + v.y*v.y + v.z*v.z + v.w*v.w;
  #pragma unroll
  for (int off = 32; off > 0; off >>= 1) {
    s  += __shfl_down(s, off);
    s2 += __shfl_down(s2, off);
  }
  __shared__ float rs[4], rs2[4], stats[2];
  int lane = t & 63, wave = t >> 6;
  if (lane == 0) { rs[wave] = s; rs2[wave] = s2; }
  __syncthreads();
  if (t == 0) {
    float ts  = rs[0] + rs[1] + rs[2] + rs[3];
    float ts2 = rs2[0] + rs2[1] + rs2[2] + rs2[3];
    float mu = ts / DMODEL;
    stats[0] = mu;
    stats[1] = rsqrtf(ts2 / DMODEL - mu * mu + 1e-5f);
  }
  __syncthreads();
  float mu = stats[0], rstd = stats[1];
  float4 gg = reinterpret_cast<const float4*>(g)[t];
  float4 bb = reinterpret_cast<const float4*>(b)[t];
  ushort4 o;
  o.x = f2bf((v.x - mu) * rstd * gg.x + bb.x);
  o.y = f2bf((v.y - mu) * rstd * gg.y + bb.y);
  o.z = f2bf((v.z - mu) * rstd * gg.z + bb.z);
  o.w = f2bf((v.w - mu) * rstd * gg.w + bb.w);
  reinterpret_cast<ushort4*>(out + (size_t)row * DMODEL)[t] = o;
}

// ---- bf16 tile transpose: in [R][C] (row stride ldin) -> out [C][R] ----
__global__ __launch_bounds__(256) void transpose_bf16(const unsigned short* __restrict__ in,
                                                      unsigned short* __restrict__ out,
                                                      int R, int C, int ldin,
                                                      size_t sIn, size_t sOut) {
  __shared__ unsigned short tile[32][33];
  in  += (size_t)blockIdx.z * sIn;
  out += (size_t)blockIdx.z * sOut;
  int c0 = blockIdx.x * 32, r0 = blockIdx.y * 32;
  int tx = threadIdx.x & 31, ty = threadIdx.x >> 5;  // 32 x 8
  #pragma unroll
  for (int i = 0; i < 4; ++i)
    tile[ty + i * 8][tx] = in[(size_t)(r0 + ty + i * 8) * ldin + c0 + tx];
  __syncthreads();
  #pragma unroll
  for (int i = 0; i < 4; ++i)
    out[(size_t)(c0 + ty + i * 8) * R + r0 + tx] = tile[tx][ty + i * 8];
}

// ---- causal row softmax: bf16 scores -> bf16 probs; writes only the
// k-range PV will read (k < ceil((q+1)/128)*128) ----
__global__ __launch_bounds__(256) void softmax_causal(const unsigned short* __restrict__ Sc,
                                                      unsigned short* __restrict__ P) {
  const int q = blockIdx.x, b = blockIdx.y;
  const unsigned short* srow = Sc + ((size_t)b * SEQ + q) * SEQ;
  unsigned short* prow = P + ((size_t)b * SEQ + q) * SEQ;
  const int L = q + 1;
  const int kcap = (q & ~127) + 128;   // PV reads k < m0+128 = kcap for row q
  const int t = threadIdx.x;
  __shared__ float red[4];
  __shared__ float bc;

  float mx = -1e30f;
  for (int i = t; i < L; i += 256) mx = fmaxf(mx, bf2f(srow[i]));
  #pragma unroll
  for (int off = 32; off > 0; off >>= 1) mx = fmaxf(mx, __shfl_down(mx, off));
  if ((t & 63) == 0) red[t >> 6] = mx;
  __syncthreads();
  if (t == 0) bc = fmaxf(fmaxf(red[0], red[1]), fmaxf(red[2], red[3]));
  __syncthreads();
  mx = bc;

  float sum = 0.f;
  for (int i = t; i < L; i += 256) sum += __expf(bf2f(srow[i]) - mx);
  #pragma unroll
  for (int off = 32; off > 0; off >>= 1) sum += __shfl_down(sum, off);
  __syncthreads();            // red reuse guard
  if ((t & 63) == 0) red[t >> 6] = sum;
  __syncthreads();
  if (t == 0) bc = 1.0f / (red[0] + red[1] + red[2] + red[3]);
  __syncthreads();
  float inv = bc;

  for (int i = t; i < kcap; i += 256) {
    float p = (i < L) ? __expf(bf2f(srow[i]) - mx) * inv : 0.f;
    prow[i] = f2bf(p);
  }
}

// ---------------------------------------------------------------------------
// 128x128 GEMM (scores / PV / Wo / FC2): 4 waves (2x2 of 64x64), BK=64,
// dbuf LDS, COUNTED-VMCNT pipeline (r16 gemm_bt256 skeleton, 8 loads/wave
// per stage): prologue stage(0),stage(1); loop { wait vmcnt(8); ACQ; MFMA;
// REL; stage(it+2) } -- the DMA queue never drains, so both co-resident
// blocks' streams stay fed continuously (vs __syncthreads' vmcnt(0) drain
// once per iter). XOR swizzle (0 bank conflicts), 8x8 super-tile remap.
// ---------------------------------------------------------------------------
template<bool OUT_F32, bool ADD_BIAS, bool RELU, bool ADD_RESID,
         bool CAUSAL_SKIP, bool CAUSAL_KLIM, bool SCALE>
__global__ __launch_bounds__(256) void gemm_bt(
    const unsigned short* __restrict__ A, size_t sA,
    const unsigned short* __restrict__ B, size_t sB,
    void* __restrict__ Cv, size_t sC,
    const float* __restrict__ bias,
    const float* __restrict__ resid, size_t sR,
    int K, int lda, int ldb, int ldc, float scale) {
  const int GX = gridDim.x;                    // m-blocks (multiple of 8)
  const int linear = blockIdx.y * GX + blockIdx.x;
  const int tileId = linear >> 6;
  const int within = linear & 63;
  const int mGroups = GX >> 3;
  const int m_blk = (tileId % mGroups) * 8 + (within & 7);
  const int n_blk = (tileId / mGroups) * 8 + (within >> 3);
  const int m0 = m_blk * 128;
  const int n0 = n_blk * 128;
  if (CAUSAL_SKIP && n0 > m0 + 127) return;  // block fully masked
  const int bz = blockIdx.z;
  A += (size_t)bz * sA;
  B += (size_t)bz * sB;

  __shared__ unsigned short As[2][128 * 64];   // 2 x 16 KB, XOR-swizzled
  __shared__ unsigned short Bs[2][128 * 64];

  const int t = threadIdx.x;
  const int lane = t & 63;
  const int wave = t >> 6;
  const int wm = (wave >> 1) * 64;
  const int wn = (wave & 1) * 64;
  const int lr = lane & 15;
  const int lq = lane >> 4;

  const int srow = lane >> 3;                  // 0..7
  const int pcol = ((lane & 7) ^ srow) * 8;    // XOR-swizzled fetch col

  f32x4 acc[4][4] = {};

  const int kEnd  = CAUSAL_KLIM ? min(K, m0 + 128) : K;
  const int nIter = kEnd >> 6;                 // BK = 64 (>= 2 for all uses)

  auto stage = [&](int buf, int kt) {
    #pragma unroll
    for (int i = 0; i < 4; ++i) {
      const int c = wave * 4 + i;              // chunk 0..15
      const int row = c * 8 + srow;
      g2l16(&A[(size_t)(m0 + row) * lda + kt + pcol], &As[buf][c * 512]);
      g2l16(&B[(size_t)(n0 + row) * ldb + kt + pcol], &Bs[buf][c * 512]);
    }
  };

  stage(0, 0);                     // 8 loads/wave
  if (nIter > 1) stage(1, 64);     // 8 more -> 16 outstanding/wave

  for (int it = 0; it < nIter; ++it) {
    // own stage(it) complete; stage(it+1)'s 8 loads may remain in flight
    if (it + 1 < nIter) asm volatile("s_waitcnt vmcnt(8)" ::: "memory");
    else                asm volatile("s_waitcnt vmcnt(0)" ::: "memory");
    BAR_ACQ();         // all waves' stage(it) complete
    const unsigned short* Ab = As[it & 1];
    const unsigned short* Bb = Bs[it & 1];
    #pragma unroll
    for (int kk = 0; kk < 2; ++kk) {
      short8 af[4], bfr[4];
      #pragma unroll
      for (int i = 0; i < 4; ++i) {
        const int r = wm + i * 16 + lr;
        af[i] = *reinterpret_cast<const short8*>(
            &Ab[r * 64 + (((kk * 4 + lq) ^ (r & 7)) * 8)]);
      }
      #pragma unroll
      for (int j = 0; j < 4; ++j) {
        const int r = wn + j * 16 + lr;
        bfr[j] = *reinterpret_cast<const short8*>(
            &Bb[r * 64 + (((kk * 4 + lq) ^ (r & 7)) * 8)]);
      }
      #pragma unroll
      for (int i = 0; i < 4; ++i)
        #pragma unroll
        for (int j = 0; j < 4; ++j)
          acc[i][j] = __builtin_amdgcn_mfma_f32_16x16x32_bf16(af[i], bfr[j], acc[i][j], 0, 0, 0);
    }
    BAR_REL();         // all waves done reading buf[it&1]
    if (it + 2 < nIter) stage(it & 1, (it + 2) << 6);
  }

  float* Cf = (float*)Cv + (size_t)bz * sC;
  unsigned short* Ch = (unsigned short*)Cv + (size_t)bz * sC;
  const float* rr = ADD_RESID ? (resid + (size_t)bz * sR) : nullptr;
  #pragma unroll
  for (int i = 0; i < 4; ++i) {
    #pragma unroll
    for (int j = 0; j < 4; ++j) {
      #pragma unroll
      for (int r = 0; r < 4; ++r) {
        // C/D layout (verified m89/m91): col = lane&15, row = (lane>>4)*4 + reg
        int row = m0 + wm + i * 16 + lq * 4 + r;
        int col = n0 + wn + j * 16 + lr;
        float v = acc[i][j][r];
        if (SCALE)     v *= scale;
        if (ADD_BIAS)  v += bias[col];
        if (RELU)      v = fmaxf(v, 0.0f);
        if (ADD_RESID) v += rr[(size_t)row * ldc + col];
        if (OUT_F32) Cf[(size_t)row * ldc + col] = v;
        else         Ch[(size_t)row * ldc + col] = f2bf(v);
      }
    }
  }
}

// ---------------------------------------------------------------------------
// 256x256 GEMM (FC1 / QKV): 1024 threads = 16 waves (4x4 of 64x64), BK=64,
// dbuf 128 KB LDS, counted-vmcnt pipeline (per-wave 4 loads/stage, wait
// vmcnt(4) leaves the next stage in flight across both raw barriers).
// (r16 kernel: 8x8 supertile when GY%8==0, else identity.)
// ---------------------------------------------------------------------------
template<bool OUT_F32, bool ADD_BIAS, bool RELU>
__global__ __launch_bounds__(1024) void gemm_bt256(
    const unsigned short* __restrict__ A,
    const unsigned short* __restrict__ B,
    void* __restrict__ Cv,
    const float* __restrict__ bias,
    int K, int lda, int ldb, int ldc) {
  int m_blk, n_blk;
  if ((gridDim.y & 7) == 0) {                  // 8x8 super-tile remap
    const int GX = gridDim.x;
    const int linear = blockIdx.y * GX + blockIdx.x;
    const int tileId = linear >> 6;
    const int within = linear & 63;
    const int mGroups = GX >> 3;
    m_blk = (tileId % mGroups) * 8 + (within & 7);
    n_blk = (tileId / mGroups) * 8 + (within >> 3);
  } else {                                     // identity (e.g. QKV GY=12)
    m_blk = blockIdx.x;
    n_blk = blockIdx.y;
  }
  const int m0 = m_blk * 256;
  const int n0 = n_blk * 256;

  __shared__ unsigned short As[2][256 * 64];   // 2 x 32 KB, XOR-swizzled
  __shared__ unsigned short Bs[2][256 * 64];   // 2 x 32 KB  (128 KB total)

  const int t = threadIdx.x;
  const int lane = t & 63;
  const int wave = t >> 6;                     // 0..15
  const int wm = (wave >> 2) * 64;             // 0,64,128,192
  const int wn = (wave & 3) * 64;              // 0,64,128,192
  const int lr = lane & 15;
  const int lq = lane >> 4;

  const int srow = lane >> 3;                  // 0..7
  const int pcol = ((lane & 7) ^ srow) * 8;    // XOR-swizzled fetch col

  f32x4 acc[4][4] = {};
  const int nIter = K >> 6;                    // BK = 64 (nIter >= 2 here)

  auto stage = [&](int buf, int kt) {
    #pragma unroll
    for (int i = 0; i < 2; ++i) {
      const int c = wave * 2 + i;              // chunk 0..31
      const int row = c * 8 + srow;
      g2l16(&A[(size_t)(m0 + row) * lda + kt + pcol], &As[buf][c * 512]);
      g2l16(&B[(size_t)(n0 + row) * ldb + kt + pcol], &Bs[buf][c * 512]);
    }
  };

  stage(0, 0);        // 4 loads/wave
  stage(1, 64);       // 4 more -> 8 outstanding/wave

  for (int it = 0; it < nIter; ++it) {
    // own stage(it) complete; stage(it+1)'s 4 loads may remain in flight
    if (it + 1 < nIter) asm volatile("s_waitcnt vmcnt(4)" ::: "memory");
    else                asm volatile("s_waitcnt vmcnt(0)" ::: "memory");
    BAR_ACQ();         // all waves' stage(it) complete
    const unsigned short* Ab = As[it & 1];
    const unsigned short* Bb = Bs[it & 1];
    #pragma unroll
    for (int kk = 0; kk < 2; ++kk) {
      short8 af[4], bfr[4];
      #pragma unroll
      for (int i = 0; i < 4; ++i) {
        const int r = wm + i * 16 + lr;
        af[i] = *reinterpret_cast<const short8*>(
            &Ab[r * 64 + (((kk * 4 + lq) ^ (r & 7)) * 8)]);
      }
      #pragma unroll
      for (int j = 0; j < 4; ++j) {
        const int r = wn + j * 16 + lr;
        bfr[j] = *reinterpret_cast<const short8*>(
            &Bb[r * 64 + (((kk * 4 + lq) ^ (r & 7)) * 8)]);
      }
      #pragma unroll
      for (int i = 0; i < 4; ++i)
        #pragma unroll
        for (int j = 0; j < 4; ++j)
          acc[i][j] = __builtin_amdgcn_mfma_f32_16x16x32_bf16(af[i], bfr[j], acc[i][j], 0, 0, 0);
    }
    BAR_REL();         // all waves done reading buf[it&1]
    if (it + 2 < nIter) stage(it & 1, (it + 2) << 6);
  }

  float* Cf = (float*)Cv;
  unsigned short* Ch = (unsigned short*)Cv;
  #pragma unroll
  for (int i = 0; i < 4; ++i) {
    #pragma unroll
    for (int j = 0; j < 4; ++j) {
      #pragma unroll
      for (int r = 0; r < 4; ++r) {
        int row = m0 + wm + i * 16 + lq * 4 + r;
        int col = n0 + wn + j * 16 + lr;
        float v = acc[i][j][r];
        if (ADD_BIAS) v += bias[col];
        if (RELU)     v = fmaxf(v, 0.0f);
        if (OUT_F32) Cf[(size_t)row * ldc + col] = v;
        else         Ch[(size_t)row * ldc + col] = f2bf(v);
      }
    }
  }
}

// ---------------------------------------------------------------------------
extern "C" void kernel_launch(void* const* d_in, const int* in_sizes, int n_in,
                              void* d_out, int out_size, void* d_ws, size_t ws_size,
                              hipStream_t stream) {
  const float* x    = (const float*)d_in[0];
  const float* Wq   = (const float*)d_in[1];
  const float* Wk   = (const float*)d_in[2];
  const float* Wv   = (const float*)d_in[3];
  const float* Wo   = (const float*)d_in[4];
  const float* fc1w = (const float*)d_in[5];
  const float* fc1b = (const float*)d_in[6];
  const float* fc2w = (const float*)d_in[7];
  const float* fc2b = (const float*)d_in[8];
  const float* ln1g = (const float*)d_in[9];
  const float* ln1b = (const float*)d_in[10];
  const float* ln2g = (const float*)d_in[11];
  const float* ln2b = (const float*)d_in[12];
  float* out = (float*)d_out;

  // workspace carve-up with liveness aliasing
  char* w = (char*)d_ws;
  auto alloc = [&](size_t bytes) {
    char* p = w;
    w += (bytes + 255) & ~(size_t)255;
    return p;
  };
  typedef unsigned short u16;
  u16* wqkv_b = (u16*)alloc((size_t)QKVN * DMODEL * 2);   // stacked Q|K|V
  u16* wq_b   = wqkv_b;
  u16* wk_b   = wqkv_b + (size_t)DMODEL * DMODEL;
  u16* wv_b   = wqkv_b + (size_t)2 * DMODEL * DMODEL;
  u16* wo_b   = (u16*)alloc((size_t)DMODEL * DMODEL * 2);
  u16* fc1w_b = (u16*)alloc((size_t)DFF * DMODEL * 2);
  u16* fc2w_b = (u16*)alloc((size_t)DMODEL * DFF * 2);
  u16* xn     = (u16*)alloc((size_t)NROWS * DMODEL * 2);
  u16* qkv    = (u16*)alloc((size_t)NROWS * QKVN * 2);    // 48 MB
  u16* vt     = (u16*)alloc((size_t)NROWS * DMODEL * 2);
  u16* ctx    = (u16*)alloc((size_t)NROWS * DMODEL * 2);
  u16* xn2    = (u16*)alloc((size_t)NROWS * DMODEL * 2);
  // Region A (64 MB): sc_h (bf16 scores, steps 5-6) aliased with hbuf (10-11)
  char* regA  = (char*)alloc((size_t)NB * SEQ * SEQ * 4);
  u16*   sc_h = (u16*)regA;
  u16*   hbuf = (u16*)regA;
  // Region B (32 MB): Pbuf (steps 6-7) aliased with x1 (steps 8-11)
  char* regB  = (char*)alloc((size_t)NB * SEQ * SEQ * 2);
  u16*   Pbuf = (u16*)regB;
  float* x1   = (float*)regB;

  // 1. weights -> bf16 (single launch; z selects tensor)
  {
    int n_small = DMODEL * DMODEL / 4;
    int n_big   = DFF * DMODEL / 4;
    dim3 g((n_big + 255) / 256, 6);
    cvt_bf16_all<<<g, 256, 0, stream>>>(Wq, Wk, Wv, Wo, fc1w, fc2w,
                                        wq_b, wk_b, wv_b, wo_b, fc1w_b, fc2w_b,
                                        n_small, n_big);
  }

  // 2. LN1
  ln_bf16<<<dim3(NROWS), 256, 0, stream>>>(x, ln1g, ln1b, xn);

  // 3. merged QKV projection: [8192,1024] x [3072,1024]^T -> qkv [8192,3072]
  //    256x256 dbuf counted-vmcnt, grid 32x12 = 384 blocks (identity map)
  gemm_bt256<false,false,false><<<dim3(NROWS / 256, QKVN / 256), 1024, 0, stream>>>(
      xn, wqkv_b, qkv, nullptr, DMODEL, DMODEL, DMODEL, QKVN);
  const u16* qb = qkv;                 // lda = QKVN
  const u16* kb = qkv + DMODEL;
  const u16* vb = qkv + 2 * DMODEL;

  // 4. V^T per batch: [2048,1024] (stride 3072) -> [1024,2048]
  transpose_bf16<<<dim3(DMODEL / 32, SEQ / 32, NB), 256, 0, stream>>>(
      vb, vt, SEQ, DMODEL, QKVN, (size_t)SEQ * QKVN, (size_t)DMODEL * SEQ);

  // 5. scores = Q K^T / sqrt(D), bf16 out, skip fully-masked blocks
  {
    dim3 g(SEQ / 128, SEQ / 128, NB);
    gemm_bt<false,false,false,false,true,false,true><<<g, 256, 0, stream>>>(
        qb, (size_t)SEQ * QKVN, kb, (size_t)SEQ * QKVN, sc_h, (size_t)SEQ * SEQ,
        nullptr, nullptr, 0, DMODEL, QKVN, QKVN, SEQ, 0.03125f /*1/sqrt(1024)*/);
  }

  // 6. causal softmax (bf16 in/out; writes only k < ceil((q+1)/128)*128)
  softmax_causal<<<dim3(SEQ, NB), 256, 0, stream>>>(sc_h, Pbuf);

  // 7. ctx = P V  (K-reduction bounded by causality)
  {
    dim3 g(SEQ / 128, DMODEL / 128, NB);
    gemm_bt<false,false,false,false,false,true,false><<<g, 256, 0, stream>>>(
        Pbuf, (size_t)SEQ * SEQ, vt, (size_t)DMODEL * SEQ, ctx, (size_t)SEQ * DMODEL,
        nullptr, nullptr, 0, SEQ, SEQ, SEQ, DMODEL, 1.f);
  }

  // 8. x1 = x + ctx Wo^T  (fp32)  -- x1 aliases Pbuf (dead after step 7)
  {
    dim3 g(NROWS / 128, DMODEL / 128, 1);
    gemm_bt<true,false,false,true,false,false,false><<<g, 256, 0, stream>>>(
        ctx, 0, wo_b, 0, x1, 0, nullptr, x, 0, DMODEL, DMODEL, DMODEL, DMODEL, 1.f);
  }

  // 9. LN2
  ln_bf16<<<dim3(NROWS), 256, 0, stream>>>(x1, ln2g, ln2b, xn2);

  // 10. h = relu(xn2 fc1_w^T + fc1_b)  bf16 [8192,4096]
  //     256x256 dbuf counted-vmcnt, grid 32x16 = 512 blocks
  gemm_bt256<false,true,true><<<dim3(NROWS / 256, DFF / 256), 1024, 0, stream>>>(
      xn2, fc1w_b, hbuf, fc1b, DMODEL, DMODEL, DMODEL, DFF);

  // 11. out = x1 + h fc2_w^T + fc2_b  (fp32)
  //     128x128 dbuf counted-vmcnt, grid 64x8 = 512 blocks = 2/CU
  {
    dim3 g(NROWS / 128, DMODEL / 128, 1);
    gemm_bt<true,true,false,true,false,false,false><<<g, 256, 0, stream>>>(
        hbuf, 0, fc2w_b, 0, out, 0, fc2b, x1, 0, DFF, DFF, DFF, DMODEL, 1.f);
  }
}